// Round 1
// baseline (1639.115 us; speedup 1.0000x reference)
//
#include <hip/hip_runtime.h>

#define NN 16384
#define DD 32
#define NJ 8
#define TPB1 128
#define JCH (NN / NJ)
#define TPB2 64

// ---------------- K1: partial[c][i][:] = sum_{j in chunk c, adj[j][i]!=0} x[j][:]
template<int ATOMIC>
__global__ __launch_bounds__(TPB1) void k_agg(const int* __restrict__ adj,
                                              const float* __restrict__ x,
                                              float* __restrict__ part) {
  const int i = blockIdx.x * TPB1 + threadIdx.x;   // column (dst node)
  const int c = blockIdx.y;                        // j-chunk
  const size_t j0 = (size_t)c * JCH;
  float acc[DD];
#pragma unroll
  for (int d = 0; d < DD; ++d) acc[d] = 0.f;
  int any = 0;
  const int* p = adj + j0 * NN + i;
  for (int jj = 0; jj < JCH; jj += 8) {
    int v[8];
#pragma unroll
    for (int u = 0; u < 8; ++u) v[u] = __builtin_nontemporal_load(p + (size_t)u * NN);
    p += (size_t)8 * NN;
#pragma unroll
    for (int u = 0; u < 8; ++u) {
      if (v[u]) {                      // rare (wave-level taken ~12%)
        any = 1;
        const float4* xr = (const float4*)(x + (j0 + jj + u) * DD);
#pragma unroll
        for (int q = 0; q < 8; ++q) {
          float4 xv = xr[q];
          acc[4*q+0] += xv.x; acc[4*q+1] += xv.y;
          acc[4*q+2] += xv.z; acc[4*q+3] += xv.w;
        }
      }
    }
  }
  if (ATOMIC) {
    if (any) {
      float* dst = part + (size_t)i * DD;
#pragma unroll
      for (int d = 0; d < DD; ++d) atomicAdd(dst + d, acc[d]);
    }
  } else {
    float4* dst = (float4*)(part + ((size_t)c * NN + i) * DD);
#pragma unroll
    for (int q = 0; q < 8; ++q)
      dst[q] = make_float4(acc[4*q], acc[4*q+1], acc[4*q+2], acc[4*q+3]);
  }
}

// ---------------- K2: h1 = (x + sum_c partial)@W1 + b1; BN sum/sumsq
__global__ __launch_bounds__(TPB2) void k_mlp1(const float* __restrict__ x,
                                               const float* __restrict__ part, int nbuf,
                                               const float* __restrict__ W1,
                                               const float* __restrict__ b1,
                                               float* __restrict__ h1,
                                               float* __restrict__ stats) {
  __shared__ float sW[DD * DD];
  __shared__ float sb[DD];
  for (int t = threadIdx.x; t < DD * DD; t += TPB2) sW[t] = W1[t];
  if (threadIdx.x < DD) sb[threadIdx.x] = b1[threadIdx.x];
  __syncthreads();
  const int i = blockIdx.x * TPB2 + threadIdx.x;
  float hin[DD];
  const float4* xr = (const float4*)(x + (size_t)i * DD);
#pragma unroll
  for (int q = 0; q < 8; ++q) {
    float4 v = xr[q];
    hin[4*q] = v.x; hin[4*q+1] = v.y; hin[4*q+2] = v.z; hin[4*q+3] = v.w;
  }
  for (int c = 0; c < nbuf; ++c) {
    const float4* pr = (const float4*)(part + ((size_t)c * NN + i) * DD);
#pragma unroll
    for (int q = 0; q < 8; ++q) {
      float4 v = pr[q];
      hin[4*q] += v.x; hin[4*q+1] += v.y; hin[4*q+2] += v.z; hin[4*q+3] += v.w;
    }
  }
  float h[DD];
#pragma unroll
  for (int d = 0; d < DD; ++d) h[d] = sb[d];
  const float4* sW4 = (const float4*)sW;
#pragma unroll 4
  for (int k = 0; k < DD; ++k) {
    float hk = hin[k];
#pragma unroll
    for (int q = 0; q < 8; ++q) {
      float4 w = sW4[k*8 + q];
      h[4*q+0] += hk*w.x; h[4*q+1] += hk*w.y;
      h[4*q+2] += hk*w.z; h[4*q+3] += hk*w.w;
    }
  }
  float4* hw = (float4*)(h1 + (size_t)i * DD);
#pragma unroll
  for (int q = 0; q < 8; ++q)
    hw[q] = make_float4(h[4*q], h[4*q+1], h[4*q+2], h[4*q+3]);
  // BN stats: butterfly over the wave, one atomic per column per wave
#pragma unroll
  for (int d = 0; d < DD; ++d) {
    float s = h[d], ss = h[d] * h[d];
#pragma unroll
    for (int off = 32; off > 0; off >>= 1) {
      s += __shfl_xor(s, off);
      ss += __shfl_xor(ss, off);
    }
    if (threadIdx.x == 0) {
      atomicAdd(&stats[d], s);
      atomicAdd(&stats[DD + d], ss);
    }
  }
}

// ---------------- K3: fold BN stats into scale/shift
__global__ void k_bn(const float* __restrict__ gamma, const float* __restrict__ beta,
                     float* __restrict__ stats) {
  int d = threadIdx.x;
  if (d < DD) {
    float mu = stats[d] * (1.0f / NN);
    float var = stats[DD + d] * (1.0f / NN) - mu * mu;
    float sc = gamma[d] * rsqrtf(var + 1e-5f);
    stats[96 + d] = sc;                 // scale
    stats[128 + d] = beta[d] - mu * sc; // shift
  }
}

// ---------------- K4: hn = relu(h1*sc+sh); h2 = relu(hn@W2+b2); pool += sum(h2)
__global__ __launch_bounds__(TPB2) void k_mlp2(const float* __restrict__ h1,
                                               const float* __restrict__ W2,
                                               const float* __restrict__ b2,
                                               float* __restrict__ stats) {
  __shared__ float sW[DD * DD];
  __shared__ float sb[DD], ssc[DD], ssh[DD];
  for (int t = threadIdx.x; t < DD * DD; t += TPB2) sW[t] = W2[t];
  if (threadIdx.x < DD) {
    sb[threadIdx.x] = b2[threadIdx.x];
    ssc[threadIdx.x] = stats[96 + threadIdx.x];
    ssh[threadIdx.x] = stats[128 + threadIdx.x];
  }
  __syncthreads();
  const int i = blockIdx.x * TPB2 + threadIdx.x;
  float hn[DD];
  const float4* hr = (const float4*)(h1 + (size_t)i * DD);
#pragma unroll
  for (int q = 0; q < 8; ++q) {
    float4 v = hr[q];
    hn[4*q] = v.x; hn[4*q+1] = v.y; hn[4*q+2] = v.z; hn[4*q+3] = v.w;
  }
#pragma unroll
  for (int d = 0; d < DD; ++d) hn[d] = fmaxf(hn[d] * ssc[d] + ssh[d], 0.f);
  float h[DD];
#pragma unroll
  for (int d = 0; d < DD; ++d) h[d] = sb[d];
  const float4* sW4 = (const float4*)sW;
#pragma unroll 4
  for (int k = 0; k < DD; ++k) {
    float hk = hn[k];
#pragma unroll
    for (int q = 0; q < 8; ++q) {
      float4 w = sW4[k*8 + q];
      h[4*q+0] += hk*w.x; h[4*q+1] += hk*w.y;
      h[4*q+2] += hk*w.z; h[4*q+3] += hk*w.w;
    }
  }
#pragma unroll
  for (int d = 0; d < DD; ++d) {
    float s = fmaxf(h[d], 0.f);
#pragma unroll
    for (int off = 32; off > 0; off >>= 1) s += __shfl_xor(s, off);
    if (threadIdx.x == 0) atomicAdd(&stats[64 + d], s);
  }
}

// ---------------- K5: out = (pool/N)@Wf + bf
__global__ void k_fc(const float* __restrict__ stats, const float* __restrict__ Wf,
                     const float* __restrict__ bf, float* __restrict__ out) {
  int o = threadIdx.x;
  if (o < 16) {
    float acc = bf[o];
#pragma unroll
    for (int d = 0; d < DD; ++d)
      acc += stats[64 + d] * (1.0f / NN) * Wf[d * 16 + o];
    out[o] = acc;
  }
}

extern "C" void kernel_launch(void* const* d_in, const int* in_sizes, int n_in,
                              void* d_out, int out_size, void* d_ws, size_t ws_size,
                              hipStream_t stream) {
  const float* x     = (const float*)d_in[0];
  const int*   adj   = (const int*)d_in[1];
  const float* W1    = (const float*)d_in[2];
  const float* b1    = (const float*)d_in[3];
  const float* gamma = (const float*)d_in[4];
  const float* beta  = (const float*)d_in[5];
  const float* W2    = (const float*)d_in[6];
  const float* b2    = (const float*)d_in[7];
  const float* Wf    = (const float*)d_in[8];
  const float* bf    = (const float*)d_in[9];
  float* out = (float*)d_out;

  // ws layout: stats[256] | h1[N*32] | part[NJ*N*32]
  float* stats = (float*)d_ws;
  float* h1 = stats + 256;
  float* part = h1 + (size_t)NN * DD;
  const size_t base_bytes = (256 + (size_t)NN * DD) * sizeof(float);
  const size_t part_bytes = (size_t)NJ * NN * DD * sizeof(float);
  const bool use_partials = ws_size >= base_bytes + part_bytes;
  const int nbuf = use_partials ? NJ : 1;

  hipMemsetAsync(d_ws, 0, 256 * sizeof(float), stream);  // sum/sumsq/pool
  dim3 g1(NN / TPB1, NJ);
  if (use_partials) {
    k_agg<0><<<g1, TPB1, 0, stream>>>(adj, x, part);
  } else {
    hipMemsetAsync(part, 0, (size_t)NN * DD * sizeof(float), stream);
    k_agg<1><<<g1, TPB1, 0, stream>>>(adj, x, part);
  }
  k_mlp1<<<NN / TPB2, TPB2, 0, stream>>>(x, part, nbuf, W1, b1, h1, stats);
  k_bn<<<1, 64, 0, stream>>>(gamma, beta, stats);
  k_mlp2<<<NN / TPB2, TPB2, 0, stream>>>(h1, W2, b2, stats);
  k_fc<<<1, 64, 0, stream>>>(stats, Wf, bf, out);
}